// Round 15
// baseline (116.916 us; speedup 1.0000x reference)
//
#include <hip/hip_runtime.h>

typedef unsigned short u16;
typedef unsigned int u32;
typedef float f32x4 __attribute__((ext_vector_type(4)));
typedef float f32x16 __attribute__((ext_vector_type(16)));
typedef unsigned int u32x4 __attribute__((ext_vector_type(4)));
typedef unsigned int u32x2 __attribute__((ext_vector_type(2)));
typedef unsigned short u16x8 __attribute__((ext_vector_type(8)));
typedef unsigned short u16x4 __attribute__((ext_vector_type(4)));

#define DEV static __device__ __forceinline__

constexpr int BB = 2, TT = 2048, CC = 1024, HH = 16, DD = 64;
constexpr int MDIM = BB * TT;  // 4096

DEV u16 f2bf(float f) {
  unsigned int u = __builtin_bit_cast(unsigned int, f);
  u += 0x7fffu + ((u >> 16) & 1u);
  return (u16)(u >> 16);
}
DEV float bf2f(u16 h) {
  unsigned int u = ((unsigned int)h) << 16;
  return __builtin_bit_cast(float, u);
}
DEV void async16(const void* g, void* l) {
  __builtin_amdgcn_global_load_lds(
      (const __attribute__((address_space(1))) unsigned int*)g,
      (__attribute__((address_space(3))) unsigned int*)l, 16, 0, 0);
}
DEV void mfma16(f32x4& acc, u32x4 a, u32x4 b) {
  asm volatile("v_mfma_f32_16x16x32_bf16 %0, %1, %2, %0"
               : "+v"(acc)
               : "v"(a), "v"(b));
}
DEV u32 cvtpk(float lo, float hi) {
  u32 r;
  asm("v_cvt_pk_bf16_f32 %0, %1, %2" : "=v"(r) : "v"(lo), "v"(hi));
  return r;
}
DEV float exp2g(float x) {
#if __has_builtin(__builtin_amdgcn_exp2f)
  return __builtin_amdgcn_exp2f(x);
#else
  return exp2f(x);
#endif
}

// ---------------------------------------------------------------- prep ----
__global__ void prep_all(const float* __restrict__ x,
                         const float* __restrict__ Wa, const float* __restrict__ Wp,
                         u16* __restrict__ x_bf,
                         u16* __restrict__ Wa_t, u16* __restrict__ Wp_t) {
  __shared__ float tile[32][33];
  int bx = blockIdx.x;
  const int tx = threadIdx.x, ty = threadIdx.y;
  if (bx >= 128) {
    const int cb = (bx - 128) * 32 + blockIdx.y;
    const int i = (cb * 1024 + ty * 32 + tx) * 4;
    f32x4 v = *(const f32x4*)(x + i);
    u16x4 o;
#pragma unroll
    for (int j = 0; j < 4; ++j) o[j] = f2bf(v[j]);
    *(u16x4*)(x_bf + i) = o;
    return;
  }
  const float* in;
  u16* out;
  int Cc;
  if (bx < 96) { in = Wa; out = Wa_t; Cc = 3072; }
  else { bx -= 96; in = Wp; out = Wp_t; Cc = 1024; }
  const int R = 1024;
  const int x0 = bx * 32, y0 = blockIdx.y * 32;
  tile[ty][tx] = in[(size_t)(y0 + ty) * Cc + (x0 + tx)];
  __syncthreads();
  out[(size_t)(x0 + ty) * R + (y0 + tx)] = f2bf(tile[tx][ty]);
}

// -------------------------------------------------- qkv GEMM (256x192) ----
// R13-proven: counted-vmcnt 2-deep pipeline, 256 blocks = 1/CU, 8 waves.
__global__ __launch_bounds__(512, 2) void gemm_qkv256(
    const u16* __restrict__ A, const u16* __restrict__ Bt,
    const float* __restrict__ bias,
    u16* __restrict__ qw, u16* __restrict__ kw, u16* __restrict__ vw) {
  extern __shared__ char smem[];  // A: 2x32KB @0 | B: 2x24KB @64KB = 112KB
  const int K = CC, NT = K / 64;
  const int tid = threadIdx.x;
  const int lane = tid & 63, w = tid >> 6;
  const int g = lane >> 4, c16 = lane & 15;
  const int wm2 = (w >> 2) * 128, wn2 = (w & 3) * 48;

  const int wgid = blockIdx.x;
  const int xcd = wgid & 7, idx = wgid >> 3;
  const int patch = xcd * 2 + (idx >> 4);
  const int q = idx & 15;
  const int bys = (patch & 3) * 4 + (q & 3);
  const int bxs = (patch >> 2) * 4 + (q >> 2);
  const int brow = bys * 256, bcol = bxs * 192;

  const int lrow = lane >> 3;
  const int scol = ((lane & 7) ^ lrow) << 4;
  const int rswz = (c16 & 7) << 4;

  f32x4 acc[8][3];
#pragma unroll
  for (int m = 0; m < 8; ++m)
#pragma unroll
    for (int n = 0; n < 3; ++n) acc[m][n] = f32x4{0.f, 0.f, 0.f, 0.f};

  const size_t ldb = (size_t)K * 2;
  const char* Abase = (const char*)A + (size_t)brow * ldb;
  const char* Bbase = (const char*)Bt + (size_t)bcol * ldb;

  auto STAGE = [&](int kt) {
    const int par = kt & 1;
    char* Adst = smem + par * 32768;
    char* Bdst = smem + 65536 + par * 24576;
    const size_t koff = (size_t)kt * 128;
#pragma unroll
    for (int i = 0; i < 4; ++i) {
      const int c = w * 4 + i;
      const int row = c * 8 + lrow;
      async16(Abase + (size_t)row * ldb + koff + scol, Adst + c * 1024);
    }
#pragma unroll
    for (int i = 0; i < 3; ++i) {
      const int c = w * 3 + i;
      const int row = c * 8 + lrow;
      async16(Bbase + (size_t)row * ldb + koff + scol, Bdst + c * 1024);
    }
  };

  STAGE(0);
  STAGE(1);

  for (int kt = 0; kt < NT; ++kt) {
    const int par = kt & 1;
    if (kt + 1 < NT)
      asm volatile("s_waitcnt vmcnt(7)" ::: "memory");
    else
      asm volatile("s_waitcnt vmcnt(0)" ::: "memory");
    __builtin_amdgcn_sched_barrier(0);
    __builtin_amdgcn_s_barrier();
    __builtin_amdgcn_sched_barrier(0);
    const char* Ap = smem + par * 32768;
    const char* Bp = smem + 65536 + par * 24576;
#pragma unroll
    for (int kc = 0; kc < 2; ++kc) {
      const int cb = (kc * 64 + g * 16) ^ rswz;
      u32x4 af[8], bf[3];
#pragma unroll
      for (int m = 0; m < 8; ++m)
        af[m] = *(const u32x4*)(Ap + (wm2 + m * 16 + c16) * 128 + cb);
#pragma unroll
      for (int n = 0; n < 3; ++n)
        bf[n] = *(const u32x4*)(Bp + (wn2 + n * 16 + c16) * 128 + cb);
      asm volatile("s_waitcnt lgkmcnt(0)" ::: "memory");
      __builtin_amdgcn_sched_barrier(0);
      __builtin_amdgcn_s_setprio(1);
#pragma unroll
      for (int m = 0; m < 8; ++m)
#pragma unroll
        for (int n = 0; n < 3; ++n) mfma16(acc[m][n], af[m], bf[n]);
      __builtin_amdgcn_s_setprio(0);
    }
    __builtin_amdgcn_s_barrier();
    if (kt + 2 < NT) STAGE(kt + 2);
  }

  u16* E = (u16*)smem;
#pragma unroll
  for (int n = 0; n < 3; ++n) {
    const float bv = bias[bcol + wn2 + n * 16 + c16];
#pragma unroll
    for (int m = 0; m < 8; ++m)
#pragma unroll
      for (int r = 0; r < 4; ++r)
        E[(wm2 + m * 16 + g * 4 + r) * 192 + wn2 + n * 16 + c16] =
            f2bf(acc[m][n][r] + bv);
  }
  __syncthreads();
#pragma unroll
  for (int i = 0; i < 12; ++i) {
    const int c = tid + i * 512;
    {  // row-major: q/k
      const int row = c / 24, col8 = (c % 24) * 8;
      const int colg = bcol + col8;
      if (colg < 2048) {
        const int which = colg >> 10, cc = colg & 1023, h = cc >> 6, d = cc & 63;
        const int rowg = brow + row, b = rowg >> 11, t = rowg & (TT - 1);
        u16x8 v8 = *(const u16x8*)&E[row * 192 + col8];
        u16* dst = (which == 0 ? qw : kw) + ((size_t)(b * HH + h) * TT + t) * DD + d;
        *(u16x8*)dst = v8;
      }
    }
    {  // col-major: v -> [d][t]
      const int col = c % 192, row8 = (c / 192) * 8;
      const int colg = bcol + col;
      if (colg >= 2048) {
        const int cc = colg & 1023, h = cc >> 6, d = cc & 63;
        const int rowg = brow + row8, b = rowg >> 11, t = rowg & (TT - 1);
        u16x8 v8;
#pragma unroll
        for (int j = 0; j < 8; ++j) v8[j] = E[(row8 + j) * 192 + col];
        u16* dst = vw + ((size_t)(b * HH + h) * DD + d) * TT + t;
        *(u16x8*)dst = v8;
      }
    }
  }
}

// ----------------------------------------------------------- proj GEMM ----
__global__ __launch_bounds__(256) void gemm_proj(
    const u16* __restrict__ A, const u16* __restrict__ Bt,
    const float* __restrict__ bias, float* __restrict__ outF,
    int M, int N, int K) {
  __shared__ alignas(16) u16 Sh[2][128 * 64];
  u16* Asp = Sh[0];
  u16* Bsp = Sh[1];
  const int tid = threadIdx.x;
  const int lane = tid & 63, w = tid >> 6;
  const int g = lane >> 4, c16 = lane & 15;
  const int wm = (w >> 1) * 64, wn = (w & 1) * 64;

  const int wgid = blockIdx.y * gridDim.x + blockIdx.x;
  const int xcd = wgid & 7, pi = wgid >> 3;
  const int bxs = pi & 7;
  const int bys = 4 * xcd + (pi >> 3);
  const int brow = bys * 128, bcol = bxs * 128;

  const int lrow = lane >> 3;
  const int scol = ((lane & 7) ^ lrow) << 4;
  const int rswz = (c16 & 7) << 4;

  f32x4 acc[4][4];
#pragma unroll
  for (int m = 0; m < 4; ++m)
#pragma unroll
    for (int n = 0; n < 4; ++n) acc[m][n] = f32x4{0.f, 0.f, 0.f, 0.f};

  const size_t ldb = (size_t)K * 2;
  const char* Abase = (const char*)A + (size_t)brow * ldb;
  const char* Bbase = (const char*)Bt + (size_t)bcol * ldb;

  for (int kt = 0; kt < K; kt += 64) {
    __syncthreads();
#pragma unroll
    for (int i = 0; i < 4; ++i) {
      const int chunk = i * 4 + w;
      const int row = chunk * 8 + lrow;
      async16(Abase + (size_t)row * ldb + (size_t)kt * 2 + scol, (char*)Asp + chunk * 1024);
      async16(Bbase + (size_t)row * ldb + (size_t)kt * 2 + scol, (char*)Bsp + chunk * 1024);
    }
    __syncthreads();
#pragma unroll
    for (int kc = 0; kc < 2; ++kc) {
      const int cb = (kc * 64 + g * 16) ^ rswz;
      u32x4 af[4], bf8[4];
#pragma unroll
      for (int m = 0; m < 4; ++m)
        af[m] = *(const u32x4*)((const char*)Asp + (wm + m * 16 + c16) * 128 + cb);
#pragma unroll
      for (int n = 0; n < 4; ++n)
        bf8[n] = *(const u32x4*)((const char*)Bsp + (wn + n * 16 + c16) * 128 + cb);
#pragma unroll
      for (int m = 0; m < 4; ++m)
#pragma unroll
        for (int n = 0; n < 4; ++n) mfma16(acc[m][n], af[m], bf8[n]);
    }
  }

  float* Ef = (float*)&Sh[0][0];
#pragma unroll
  for (int pass = 0; pass < 2; ++pass) {
    __syncthreads();
    if ((wm >> 6) == pass) {
#pragma unroll
      for (int n = 0; n < 4; ++n) {
        const float bv = bias[bcol + wn + n * 16 + c16];
#pragma unroll
        for (int m = 0; m < 4; ++m)
#pragma unroll
          for (int r = 0; r < 4; ++r)
            Ef[(m * 16 + g * 4 + r) * 128 + wn + n * 16 + c16] = acc[m][n][r] + bv;
      }
    }
    __syncthreads();
#pragma unroll
    for (int i = 0; i < 8; ++i) {
      const int chunk = tid + i * 256;
      const int row = chunk >> 5;
      const int c4 = (chunk & 31) * 4;
      f32x4 v4 = *(const f32x4*)&Ef[row * 128 + c4];
      *(f32x4*)&outF[(size_t)(brow + pass * 64 + row) * N + bcol + c4] = v4;
    }
  }
}

// ----------------------------------------------------------- attention ----
// R14: 16 q-rows/wave (16x16 MFMA) -> 4096 total waves = 4/SIMD, double the
// structural TLP ceiling that pinned R9 at 2/SIMD. 8 waves x 16 q = 128-row
// block, 512 threads; LDS 64KB (4-deep KVBLK=64) -> 2 blocks/CU = 16
// waves/CU. Same proven pipeline: QK(t+1)-ahead, counted vmcnt (2 loads/
// wave/stage -> vmcnt(2) in-loop), fixed-base softmax.
// Layouts (all from proven gemm patterns):
//   S^T = mfma16(A=K[16k x 32d], B=Q^T[32d x 16q]): lane (q=l&15, g=l>>4)
//     holds S[k = kf*16 + g*4 + r][q].
//   PV: O^T = mfma16(A=V^T[16d x 32k], B=P^T[32k x 16q]); B-frag needs
//     P[k = kc*32 + g*8 + 0..7][q] -- k regrouped 4-strided -> 8-contiguous
//     via cvtpk + ds_bpermute (src lane = q + 32*(g&1) (+16), register
//     class A/B by word parity, kf selected by g>>1).
__global__ __launch_bounds__(512) void attn_fwd(
    const u16* __restrict__ qw, const u16* __restrict__ kw,
    const u16* __restrict__ vw, u16* __restrict__ ao) {
  extern __shared__ u16 smem_a[];  // [4][64*64] K, then [4][64*64] V (64KB)
  const int tid = threadIdx.x;
  const int lane = tid & 63, w = tid >> 6;  // 8 waves
  const int q16 = lane & 15, g = lane >> 4;
  const int bh = blockIdx.y;
  const int qb = ((bh >> 4) & 1) ? (15 - blockIdx.x) : blockIdx.x;  // pairing
  const int q0w = qb * 128 + w * 16;
  const int qg = q0w + q16;
  const int lrow = lane >> 3;
  const int scol = ((lane & 7) ^ lrow) << 4;
  const int rswz = (q16 & 7) << 4;
  // bpermute source addresses (bytes = srclane*4)
  const int addr0 = (q16 + 32 * (g & 1)) * 4;
  const int addr1 = addr0 + 64;

  // Q^T B-frags: lane holds Q[qg][kc*32 + g*8 + 0..7], scaled
  u32x4 qf[2];
  {
    const u16* qrow = qw + ((size_t)bh * TT + qg) * DD;
    const float qs = 0.125f * 1.44269504f;
#pragma unroll
    for (int kc = 0; kc < 2; ++kc) {
      u16x8 u = *(const u16x8*)(qrow + kc * 32 + g * 8);
      u16x8 s;
#pragma unroll
      for (int j = 0; j < 8; ++j) s[j] = f2bf(bf2f(u[j]) * qs);
      qf[kc] = __builtin_bit_cast(u32x4, s);
    }
  }

  f32x4 o[4];
#pragma unroll
  for (int df = 0; df < 4; ++df) o[df] = f32x4{0.f, 0.f, 0.f, 0.f};
  float l_run = 0.f;

  const char* kbase = (const char*)kw + ((size_t)bh * TT) * 128;
  const char* vbase = (const char*)vw + ((size_t)bh * DD) * (TT * 2);

  const int nt = 2 * qb + 2;  // even

  auto kptr = [&](int b) { return (char*)(smem_a + (b & 3) * 4096); };
  auto vptr = [&](int b) { return (char*)(smem_a + 16384 + (b & 3) * 4096); };

  // wave w stages K chunk w + V chunk w (1KB each): 2 async16/lane
  auto STAGE = [&](int kt_) {
    if (kt_ >= nt) return;
    const int t0_ = kt_ * 64;
    const int row = w * 8 + lrow;
    async16(kbase + (size_t)(t0_ + row) * 128 + scol, kptr(kt_) + w * 1024);
    async16(vbase + (size_t)row * (TT * 2) + (size_t)t0_ * 2 + scol,
            vptr(kt_) + w * 1024);
  };

  // S^T(kt): sa[kf] = S[k = kf*16 + g*4 + r][q]
  auto QK = [&](int kt_, f32x4* sa) {
#pragma unroll
    for (int kf = 0; kf < 4; ++kf) sa[kf] = f32x4{0.f, 0.f, 0.f, 0.f};
    const char* Kc = kptr(kt_);
    __builtin_amdgcn_s_setprio(1);
#pragma unroll
    for (int kc = 0; kc < 2; ++kc) {
      const int cb = (kc * 64 + g * 16) ^ rswz;
#pragma unroll
      for (int kf = 0; kf < 4; ++kf) {
        u32x4 ak = *(const u32x4*)(Kc + (kf * 16 + q16) * 128 + cb);
        mfma16(sa[kf], ak, qf[kc]);
      }
    }
    __builtin_amdgcn_s_setprio(0);
  };

  auto FINISH = [&](int kt_, f32x4* s) {
    const int t0 = kt_ * 64;
    if (t0 >= q0w + 16) return;  // wave-uniform skip
    if (t0 + 63 > q0w) {         // causal mask, register-local
      const int kb = t0 + g * 4 - qg;
#pragma unroll
      for (int kf = 0; kf < 4; ++kf)
#pragma unroll
        for (int r = 0; r < 4; ++r)
          if (kb + kf * 16 + r > 0) s[kf][r] = -1e30f;
    }
#pragma unroll
    for (int kf = 0; kf < 4; ++kf)
#pragma unroll
      for (int r = 0; r < 4; ++r) s[kf][r] = exp2g(s[kf][r]);
    float rs = ((s[0][0] + s[0][1] + s[0][2] + s[0][3]) +
                (s[1][0] + s[1][1] + s[1][2] + s[1][3])) +
               ((s[2][0] + s[2][1] + s[2][2] + s[2][3]) +
                (s[3][0] + s[3][1] + s[3][2] + s[3][3]));
    rs += __shfl_xor(rs, 16, 64);
    rs += __shfl_xor(rs, 32, 64);
    l_run += rs;

#pragma unroll
    for (int kc = 0; kc < 2; ++kc) {
      // pack this lane's P values (k = kf*16 + g*4 + {0,1}/{2,3})
      const u32 A0 = cvtpk(s[2 * kc][0], s[2 * kc][1]);
      const u32 B0 = cvtpk(s[2 * kc][2], s[2 * kc][3]);
      const u32 A1 = cvtpk(s[2 * kc + 1][0], s[2 * kc + 1][1]);
      const u32 B1 = cvtpk(s[2 * kc + 1][2], s[2 * kc + 1][3]);
      // regroup to B-frag words: w_j = P[k = kc*32 + g*8 + 2j,2j+1][q]
      const u32 pA0 = __builtin_amdgcn_ds_bpermute(addr0, A0);
      const u32 pA1 = __builtin_amdgcn_ds_bpermute(addr0, A1);
      const u32 pB0 = __builtin_amdgcn_ds_bpermute(addr0, B0);
      const u32 pB1 = __builtin_amdgcn_ds_bpermute(addr0, B1);
      const u32 qA0 = __builtin_amdgcn_ds_bpermute(addr1, A0);
      const u32 qA1 = __builtin_amdgcn_ds_bpermute(addr1, A1);
      const u32 qB0 = __builtin_amdgcn_ds_bpermute(addr1, B0);
      const u32 qB1 = __builtin_amdgcn_ds_bpermute(addr1, B1);
      const bool hi = g >= 2;
      u32x4 pf;
      pf.x = hi ? pA1 : pA0;
      pf.y = hi ? pB1 : pB0;
      pf.z = hi ? qA1 : qA0;
      pf.w = hi ? qB1 : qB0;
      const char* Vc = vptr(kt_);
      __builtin_amdgcn_s_setprio(1);
      const int cb = (kc * 64 + g * 16) ^ rswz;
#pragma unroll
      for (int df = 0; df < 4; ++df) {
        u32x4 av = *(const u32x4*)(Vc + (df * 16 + q16) * 128 + cb);
        mfma16(o[df], av, pf);
      }
      __builtin_amdgcn_s_setprio(0);
    }
  };

  STAGE(0);
  STAGE(1);
  STAGE(2);
  if (nt >= 3)
    asm volatile("s_waitcnt vmcnt(4)" ::: "memory");
  else
    asm volatile("s_waitcnt vmcnt(2)" ::: "memory");
  __builtin_amdgcn_sched_barrier(0);
  __builtin_amdgcn_s_barrier();
  __builtin_amdgcn_sched_barrier(0);

  f32x4 sA[4], sB[4];
  QK(0, sA);

#define BODY(KT, C, N)                                                    \
  {                                                                       \
    const int kt_b = (KT);                                                \
    if (kt_b + 2 < nt)                                                    \
      asm volatile("s_waitcnt vmcnt(2)" ::: "memory");                    \
    else                                                                  \
      asm volatile("s_waitcnt vmcnt(0)" ::: "memory");                    \
    __builtin_amdgcn_sched_barrier(0);                                    \
    __builtin_amdgcn_s_barrier();                                         \
    __builtin_amdgcn_sched_barrier(0);                                    \
    STAGE(kt_b + 3);                                                      \
    if (kt_b + 1 < nt && (kt_b + 1) * 64 < q0w + 16) QK(kt_b + 1, N);     \
    FINISH(kt_b, C);                                                      \
  }

  for (int kt2 = 0; kt2 < nt; kt2 += 2) {
    BODY(kt2, sA, sB);
    BODY(kt2 + 1, sB, sA);
  }
#undef BODY

  // epilogue: lane holds O^T[d][qg], d = df*16 + g*4 + r
  const int b = bh >> 4, h = bh & 15;
  const float inv = 1.f / l_run;
  u16* aorow = ao + ((size_t)(b * TT) + qg) * CC + h * DD;
#pragma unroll
  for (int df = 0; df < 4; ++df) {
    u16x4 t4;
#pragma unroll
    for (int r = 0; r < 4; ++r) t4[r] = f2bf(o[df][r] * inv);
    *(u16x4*)(aorow + df * 16 + g * 4) = t4;
  }
}

// -------------------------------------------------------------- launch ----
extern "C" void kernel_launch(void* const* d_in, const int* in_sizes, int n_in,
                              void* d_out, int out_size, void* d_ws, size_t ws_size,
                              hipStream_t stream) {
  const float* x  = (const float*)d_in[0];
  const float* Wa = (const float*)d_in[1];
  const float* ba = (const float*)d_in[2];
  const float* Wp = (const float*)d_in[3];
  const float* bp = (const float*)d_in[4];
  float* out = (float*)d_out;

  char* ws = (char*)d_ws;
  const size_t MB = 1ull << 20;
  u16* x_bf = (u16*)(ws);            // 8 MB  [4096][1024]
  u16* ao   = (u16*)(ws);            // 8 MB  alias (x_bf dead after QKV GEMM)
  u16* Wa_t = (u16*)(ws + 8 * MB);   // 6 MB  [3072][1024]
  u16* Wp_t = (u16*)(ws + 14 * MB);  // 2 MB  [1024][1024]
  u16* q_ws = (u16*)(ws + 16 * MB);  // 8 MB  [32][2048][64]
  u16* k_ws = (u16*)(ws + 24 * MB);  // 8 MB  [32][2048][64]
  u16* v_ws = (u16*)(ws + 32 * MB);  // 8 MB  [32][64][2048]

  static bool attr_set = []() {
    hipFuncSetAttribute((const void*)gemm_qkv256,
                        hipFuncAttributeMaxDynamicSharedMemorySize, 114688);
    hipFuncSetAttribute((const void*)attn_fwd,
                        hipFuncAttributeMaxDynamicSharedMemorySize, 65536);
    return true;
  }();
  (void)attr_set;

  hipLaunchKernelGGL(prep_all, dim3(160, 32), dim3(32, 32), 0, stream,
                     x, Wa, Wp, x_bf, Wa_t, Wp_t);
  hipLaunchKernelGGL(gemm_qkv256, dim3(256), dim3(512), 114688, stream,
                     x_bf, Wa_t, ba, q_ws, k_ws, v_ws);
  hipLaunchKernelGGL(attn_fwd, dim3(TT / 128, BB * HH), dim3(512), 65536, stream,
                     q_ws, k_ws, v_ws, ao);
  hipLaunchKernelGGL(gemm_proj, dim3(CC / 128, MDIM / 128), dim3(256), 0, stream,
                     ao, Wp_t, bp, out, MDIM, CC, CC);
}

// Round 16
// 108.263 us; speedup vs baseline: 1.0799x; 1.0799x over previous
//
#include <hip/hip_runtime.h>

typedef unsigned short u16;
typedef unsigned int u32;
typedef float f32x4 __attribute__((ext_vector_type(4)));
typedef float f32x16 __attribute__((ext_vector_type(16)));
typedef unsigned int u32x4 __attribute__((ext_vector_type(4)));
typedef unsigned int u32x2 __attribute__((ext_vector_type(2)));
typedef unsigned short u16x8 __attribute__((ext_vector_type(8)));
typedef unsigned short u16x4 __attribute__((ext_vector_type(4)));

#define DEV static __device__ __forceinline__

constexpr int BB = 2, TT = 2048, CC = 1024, HH = 16, DD = 64;
constexpr int MDIM = BB * TT;  // 4096

DEV u16 f2bf(float f) {
  unsigned int u = __builtin_bit_cast(unsigned int, f);
  u += 0x7fffu + ((u >> 16) & 1u);
  return (u16)(u >> 16);
}
DEV float bf2f(u16 h) {
  unsigned int u = ((unsigned int)h) << 16;
  return __builtin_bit_cast(float, u);
}
DEV void async16(const void* g, void* l) {
  __builtin_amdgcn_global_load_lds(
      (const __attribute__((address_space(1))) unsigned int*)g,
      (__attribute__((address_space(3))) unsigned int*)l, 16, 0, 0);
}
DEV void mfma16(f32x4& acc, u32x4 a, u32x4 b) {
  asm volatile("v_mfma_f32_16x16x32_bf16 %0, %1, %2, %0"
               : "+v"(acc)
               : "v"(a), "v"(b));
}
DEV void mfma32(f32x16& acc, u32x4 a, u32x4 b) {
  asm volatile("v_mfma_f32_32x32x16_bf16 %0, %1, %2, %0"
               : "+v"(acc)
               : "v"(a), "v"(b));
}
DEV u32 cvtpk(float lo, float hi) {
  u32 r;
  asm("v_cvt_pk_bf16_f32 %0, %1, %2" : "=v"(r) : "v"(lo), "v"(hi));
  return r;
}
DEV void pswap(u32& a, u32& b) {
#if __has_builtin(__builtin_amdgcn_permlane32_swap)
  u32x2 r = __builtin_amdgcn_permlane32_swap(a, b, false, false);
  a = r.x;
  b = r.y;
#else
  asm volatile("v_permlane32_swap_b32 %0, %1" : "+v"(a), "+v"(b));
#endif
}
DEV float exp2g(float x) {
#if __has_builtin(__builtin_amdgcn_exp2f)
  return __builtin_amdgcn_exp2f(x);
#else
  return exp2f(x);
#endif
}

// ---------------------------------------------------------------- prep ----
__global__ void prep_all(const float* __restrict__ x,
                         const float* __restrict__ Wa, const float* __restrict__ Wp,
                         u16* __restrict__ x_bf,
                         u16* __restrict__ Wa_t, u16* __restrict__ Wp_t) {
  __shared__ float tile[32][33];
  int bx = blockIdx.x;
  const int tx = threadIdx.x, ty = threadIdx.y;
  if (bx >= 128) {
    const int cb = (bx - 128) * 32 + blockIdx.y;
    const int i = (cb * 1024 + ty * 32 + tx) * 4;
    f32x4 v = *(const f32x4*)(x + i);
    u16x4 o;
#pragma unroll
    for (int j = 0; j < 4; ++j) o[j] = f2bf(v[j]);
    *(u16x4*)(x_bf + i) = o;
    return;
  }
  const float* in;
  u16* out;
  int Cc;
  if (bx < 96) { in = Wa; out = Wa_t; Cc = 3072; }
  else { bx -= 96; in = Wp; out = Wp_t; Cc = 1024; }
  const int R = 1024;
  const int x0 = bx * 32, y0 = blockIdx.y * 32;
  tile[ty][tx] = in[(size_t)(y0 + ty) * Cc + (x0 + tx)];
  __syncthreads();
  out[(size_t)(x0 + ty) * R + (y0 + tx)] = f2bf(tile[tx][ty]);
}

// -------------------------------------------------- qkv GEMM (256x192) ----
// R13 structure (counted-vmcnt 2-deep pipeline, 256 blocks = 1/CU, 8 waves)
// MINUS the forced lgkmcnt(0)+sched_barrier between ds_read and MFMA: those
// ds_reads are ordinary loads the compiler tracks (rule #18 applies only to
// inline-asm ds_read), and the fence was m141-style order-pinning that
// defeats the compiler's own fine-grained lgkmcnt interleave (m97 asm).
// Barrier-adjacent sched_barrier(0) fences kept (guard the write-after-read
// hazard across the raw s_barrier).
__global__ __launch_bounds__(512, 2) void gemm_qkv256(
    const u16* __restrict__ A, const u16* __restrict__ Bt,
    const float* __restrict__ bias,
    u16* __restrict__ qw, u16* __restrict__ kw, u16* __restrict__ vw) {
  extern __shared__ char smem[];  // A: 2x32KB @0 | B: 2x24KB @64KB = 112KB
  const int K = CC, NT = K / 64;
  const int tid = threadIdx.x;
  const int lane = tid & 63, w = tid >> 6;
  const int g = lane >> 4, c16 = lane & 15;
  const int wm2 = (w >> 2) * 128, wn2 = (w & 3) * 48;

  const int wgid = blockIdx.x;
  const int xcd = wgid & 7, idx = wgid >> 3;
  const int patch = xcd * 2 + (idx >> 4);
  const int q = idx & 15;
  const int bys = (patch & 3) * 4 + (q & 3);
  const int bxs = (patch >> 2) * 4 + (q >> 2);
  const int brow = bys * 256, bcol = bxs * 192;

  const int lrow = lane >> 3;
  const int scol = ((lane & 7) ^ lrow) << 4;
  const int rswz = (c16 & 7) << 4;

  f32x4 acc[8][3];
#pragma unroll
  for (int m = 0; m < 8; ++m)
#pragma unroll
    for (int n = 0; n < 3; ++n) acc[m][n] = f32x4{0.f, 0.f, 0.f, 0.f};

  const size_t ldb = (size_t)K * 2;
  const char* Abase = (const char*)A + (size_t)brow * ldb;
  const char* Bbase = (const char*)Bt + (size_t)bcol * ldb;

  auto STAGE = [&](int kt) {
    const int par = kt & 1;
    char* Adst = smem + par * 32768;
    char* Bdst = smem + 65536 + par * 24576;
    const size_t koff = (size_t)kt * 128;
#pragma unroll
    for (int i = 0; i < 4; ++i) {
      const int c = w * 4 + i;
      const int row = c * 8 + lrow;
      async16(Abase + (size_t)row * ldb + koff + scol, Adst + c * 1024);
    }
#pragma unroll
    for (int i = 0; i < 3; ++i) {
      const int c = w * 3 + i;
      const int row = c * 8 + lrow;
      async16(Bbase + (size_t)row * ldb + koff + scol, Bdst + c * 1024);
    }
  };

  STAGE(0);
  STAGE(1);

  for (int kt = 0; kt < NT; ++kt) {
    const int par = kt & 1;
    if (kt + 1 < NT)
      asm volatile("s_waitcnt vmcnt(7)" ::: "memory");  // kt landed; kt+1 in flight
    else
      asm volatile("s_waitcnt vmcnt(0)" ::: "memory");
    __builtin_amdgcn_sched_barrier(0);
    __builtin_amdgcn_s_barrier();
    __builtin_amdgcn_sched_barrier(0);
    const char* Ap = smem + par * 32768;
    const char* Bp = smem + 65536 + par * 24576;
    // no forced lgkmcnt: compiler interleaves ds_read_b128 with MFMAs
#pragma unroll
    for (int kc = 0; kc < 2; ++kc) {
      const int cb = (kc * 64 + g * 16) ^ rswz;
      u32x4 af[8], bf[3];
#pragma unroll
      for (int m = 0; m < 8; ++m)
        af[m] = *(const u32x4*)(Ap + (wm2 + m * 16 + c16) * 128 + cb);
#pragma unroll
      for (int n = 0; n < 3; ++n)
        bf[n] = *(const u32x4*)(Bp + (wn2 + n * 16 + c16) * 128 + cb);
#pragma unroll
      for (int m = 0; m < 8; ++m)
#pragma unroll
        for (int n = 0; n < 3; ++n) mfma16(acc[m][n], af[m], bf[n]);
    }
    __builtin_amdgcn_sched_barrier(0);
    __builtin_amdgcn_s_barrier();       // all waves done reading buf[par]
    __builtin_amdgcn_sched_barrier(0);
    if (kt + 2 < NT) STAGE(kt + 2);
  }

  // ---- epilogue: stage [256][192] u16 (96KB) then 16B coalesced stores ----
  u16* E = (u16*)smem;
#pragma unroll
  for (int n = 0; n < 3; ++n) {
    const float bv = bias[bcol + wn2 + n * 16 + c16];
#pragma unroll
    for (int m = 0; m < 8; ++m)
#pragma unroll
      for (int r = 0; r < 4; ++r)
        E[(wm2 + m * 16 + g * 4 + r) * 192 + wn2 + n * 16 + c16] =
            f2bf(acc[m][n][r] + bv);
  }
  __syncthreads();
#pragma unroll
  for (int i = 0; i < 12; ++i) {
    const int c = tid + i * 512;
    {  // row-major: q/k
      const int row = c / 24, col8 = (c % 24) * 8;
      const int colg = bcol + col8;
      if (colg < 2048) {
        const int which = colg >> 10, cc = colg & 1023, h = cc >> 6, d = cc & 63;
        const int rowg = brow + row, b = rowg >> 11, t = rowg & (TT - 1);
        u16x8 v8 = *(const u16x8*)&E[row * 192 + col8];
        u16* dst = (which == 0 ? qw : kw) + ((size_t)(b * HH + h) * TT + t) * DD + d;
        *(u16x8*)dst = v8;
      }
    }
    {  // col-major: v -> [d][t]
      const int col = c % 192, row8 = (c / 192) * 8;
      const int colg = bcol + col;
      if (colg >= 2048) {
        const int cc = colg & 1023, h = cc >> 6, d = cc & 63;
        const int rowg = brow + row8, b = rowg >> 11, t = rowg & (TT - 1);
        u16x8 v8;
#pragma unroll
        for (int j = 0; j < 8; ++j) v8[j] = E[(row8 + j) * 192 + col];
        u16* dst = vw + ((size_t)(b * HH + h) * DD + d) * TT + t;
        *(u16x8*)dst = v8;
      }
    }
  }
}

// ----------------------------------------------------------- proj GEMM ----
__global__ __launch_bounds__(256) void gemm_proj(
    const u16* __restrict__ A, const u16* __restrict__ Bt,
    const float* __restrict__ bias, float* __restrict__ outF,
    int M, int N, int K) {
  __shared__ alignas(16) u16 Sh[2][128 * 64];
  u16* Asp = Sh[0];
  u16* Bsp = Sh[1];
  const int tid = threadIdx.x;
  const int lane = tid & 63, w = tid >> 6;
  const int g = lane >> 4, c16 = lane & 15;
  const int wm = (w >> 1) * 64, wn = (w & 1) * 64;

  const int wgid = blockIdx.y * gridDim.x + blockIdx.x;
  const int xcd = wgid & 7, pi = wgid >> 3;
  const int bxs = pi & 7;
  const int bys = 4 * xcd + (pi >> 3);
  const int brow = bys * 128, bcol = bxs * 128;

  const int lrow = lane >> 3;
  const int scol = ((lane & 7) ^ lrow) << 4;
  const int rswz = (c16 & 7) << 4;

  f32x4 acc[4][4];
#pragma unroll
  for (int m = 0; m < 4; ++m)
#pragma unroll
    for (int n = 0; n < 4; ++n) acc[m][n] = f32x4{0.f, 0.f, 0.f, 0.f};

  const size_t ldb = (size_t)K * 2;
  const char* Abase = (const char*)A + (size_t)brow * ldb;
  const char* Bbase = (const char*)Bt + (size_t)bcol * ldb;

  for (int kt = 0; kt < K; kt += 64) {
    __syncthreads();
#pragma unroll
    for (int i = 0; i < 4; ++i) {
      const int chunk = i * 4 + w;
      const int row = chunk * 8 + lrow;
      async16(Abase + (size_t)row * ldb + (size_t)kt * 2 + scol, (char*)Asp + chunk * 1024);
      async16(Bbase + (size_t)row * ldb + (size_t)kt * 2 + scol, (char*)Bsp + chunk * 1024);
    }
    __syncthreads();
#pragma unroll
    for (int kc = 0; kc < 2; ++kc) {
      const int cb = (kc * 64 + g * 16) ^ rswz;
      u32x4 af[4], bf8[4];
#pragma unroll
      for (int m = 0; m < 4; ++m)
        af[m] = *(const u32x4*)((const char*)Asp + (wm + m * 16 + c16) * 128 + cb);
#pragma unroll
      for (int n = 0; n < 4; ++n)
        bf8[n] = *(const u32x4*)((const char*)Bsp + (wn + n * 16 + c16) * 128 + cb);
#pragma unroll
      for (int m = 0; m < 4; ++m)
#pragma unroll
        for (int n = 0; n < 4; ++n) mfma16(acc[m][n], af[m], bf8[n]);
    }
  }

  float* Ef = (float*)&Sh[0][0];
#pragma unroll
  for (int pass = 0; pass < 2; ++pass) {
    __syncthreads();
    if ((wm >> 6) == pass) {
#pragma unroll
      for (int n = 0; n < 4; ++n) {
        const float bv = bias[bcol + wn + n * 16 + c16];
#pragma unroll
        for (int m = 0; m < 4; ++m)
#pragma unroll
          for (int r = 0; r < 4; ++r)
            Ef[(m * 16 + g * 4 + r) * 128 + wn + n * 16 + c16] = acc[m][n][r] + bv;
      }
    }
    __syncthreads();
#pragma unroll
    for (int i = 0; i < 8; ++i) {
      const int chunk = tid + i * 256;
      const int row = chunk >> 5;
      const int c4 = (chunk & 31) * 4;
      f32x4 v4 = *(const f32x4*)&Ef[row * 128 + c4];
      *(f32x4*)&outF[(size_t)(brow + pass * 64 + row) * N + bcol + c4] = v4;
    }
  }
}

// ----------------------------------------------------------- attention ----
// R9 EXACT (proven 41.8-42.2us across three rounds): swapped-operand flash
// attention, 32x32 MFMA, 4 waves x 32 q = 128-row block, 4-deep KV LDS,
// counted vmcnt, QK(t+1)-ahead in-wave pipeline, fixed-base softmax.
// R10/R11/R14 all proved restructures (smaller KV tile, split-K, 16q/wave)
// regress: the kernel is chain-bound at its local optimum.
__global__ __launch_bounds__(256) void attn_fwd(
    const u16* __restrict__ qw, const u16* __restrict__ kw,
    const u16* __restrict__ vw, u16* __restrict__ ao) {
  extern __shared__ u16 smem_a[];  // [4][64*64] K, then [4][64*64] V (64KB)
  const int tid = threadIdx.x;
  const int lane = tid & 63, w = tid >> 6;
  const int ql = lane & 31, half = lane >> 5;
  const int bh = blockIdx.y;
  const int qb = ((bh >> 4) & 1) ? (15 - blockIdx.x) : blockIdx.x;  // pairing
  const int q0w = qb * 128 + w * 32;
  const int qg = q0w + ql;
  const int lrow = lane >> 3;
  const int scol = ((lane & 7) ^ lrow) << 4;
  const int rswz = (ql & 7) << 4;

  u32x4 qf[4];
  {
    const u16* qrow = qw + ((size_t)bh * TT + qg) * DD;
    const float qs = 0.125f * 1.44269504f;
#pragma unroll
    for (int dwin = 0; dwin < 4; ++dwin) {
      u16x8 u = *(const u16x8*)(qrow + dwin * 16 + half * 8);
      u16x8 s;
#pragma unroll
      for (int j = 0; j < 8; ++j) s[j] = f2bf(bf2f(u[j]) * qs);
      qf[dwin] = __builtin_bit_cast(u32x4, s);
    }
  }

  f32x16 o0, o1;
#pragma unroll
  for (int i = 0; i < 16; ++i) { o0[i] = 0.f; o1[i] = 0.f; }
  float l_run = 0.f;

  const char* kbase = (const char*)kw + ((size_t)bh * TT) * 128;
  const char* vbase = (const char*)vw + ((size_t)bh * DD) * (TT * 2);

  const int nt = 2 * qb + 2;  // always even

  auto kptr = [&](int b) { return (char*)(smem_a + (b & 3) * 4096); };
  auto vptr = [&](int b) { return (char*)(smem_a + 16384 + (b & 3) * 4096); };

  auto STAGE = [&](int kt_) {
    if (kt_ >= nt) return;
    const int t0_ = kt_ * 64;
#pragma unroll
    for (int i_ = 0; i_ < 2; ++i_) {
      const int chunk = w * 2 + i_;
      const int row = chunk * 8 + lrow;
      async16(kbase + (size_t)(t0_ + row) * 128 + scol, kptr(kt_) + chunk * 1024);
      async16(vbase + (size_t)row * (TT * 2) + (size_t)t0_ * 2 + scol,
              vptr(kt_) + chunk * 1024);
    }
  };

  auto QK = [&](int kt_, f32x16& sa, f32x16& sb) {
    const char* Kc = kptr(kt_);
#pragma unroll
    for (int i = 0; i < 16; ++i) { sa[i] = 0.f; sb[i] = 0.f; }
    __builtin_amdgcn_s_setprio(1);
#pragma unroll
    for (int dwin = 0; dwin < 4; ++dwin) {
      const int cb = (dwin * 32 + half * 16) ^ rswz;
      u32x4 ak0 = *(const u32x4*)(Kc + (0 + ql) * 128 + cb);
      u32x4 ak1 = *(const u32x4*)(Kc + (32 + ql) * 128 + cb);
      mfma32(sa, ak0, qf[dwin]);
      mfma32(sb, ak1, qf[dwin]);
    }
    __builtin_amdgcn_s_setprio(0);
  };

  auto FINISH = [&](int kt_, f32x16& s0, f32x16& s1) {
    const int t0 = kt_ * 64;
    if (t0 >= q0w + 32) return;
    if (t0 + 63 > q0w) {
      const int kb = t0 + 4 * half - qg;
#pragma unroll
      for (int r = 0; r < 16; ++r) {
        const int ko = (r & 3) + 8 * (r >> 2);
        if (kb + ko > 0) s0[r] = -1e30f;
        if (kb + 32 + ko > 0) s1[r] = -1e30f;
      }
    }
#pragma unroll
    for (int i = 0; i < 16; ++i) {
      s0[i] = exp2g(s0[i]);
      s1[i] = exp2g(s1[i]);
    }
    float a8[8];
#pragma unroll
    for (int i = 0; i < 8; ++i)
      a8[i] = (s0[i] + s0[i + 8]) + (s1[i] + s1[i + 8]);
    float rs = ((a8[0] + a8[1]) + (a8[2] + a8[3])) + ((a8[4] + a8[5]) + (a8[6] + a8[7]));
    rs += __shfl_xor(rs, 32, 64);
    l_run += rs;

    u32x4 pf[4];
#pragma unroll
    for (int win = 0; win < 4; ++win) {
      const int b = (win & 1) * 8;
      u32 w0, w1, w2, w3;
      if (win < 2) {
        w0 = cvtpk(s0[b + 0], s0[b + 1]); w2 = cvtpk(s0[b + 4], s0[b + 5]);
        w1 = cvtpk(s0[b + 2], s0[b + 3]); w3 = cvtpk(s0[b + 6], s0[b + 7]);
      } else {
        w0 = cvtpk(s1[b + 0], s1[b + 1]); w2 = cvtpk(s1[b + 4], s1[b + 5]);
        w1 = cvtpk(s1[b + 2], s1[b + 3]); w3 = cvtpk(s1[b + 6], s1[b + 7]);
      }
      pswap(w0, w2);
      pswap(w1, w3);
      pf[win] = u32x4{w0, w1, w2, w3};
    }
    const char* Vc = vptr(kt_);
    __builtin_amdgcn_s_setprio(1);
#pragma unroll
    for (int win = 0; win < 4; ++win) {
      const int cb = (win * 32 + half * 16) ^ rswz;
      u32x4 av0 = *(const u32x4*)(Vc + (0 + ql) * 128 + cb);
      u32x4 av1 = *(const u32x4*)(Vc + (32 + ql) * 128 + cb);
      mfma32(o0, av0, pf[win]);
      mfma32(o1, av1, pf[win]);
    }
    __builtin_amdgcn_s_setprio(0);
  };

  STAGE(0);
  STAGE(1);
  STAGE(2);
  if (nt >= 3)
    asm volatile("s_waitcnt vmcnt(8)" ::: "memory");
  else
    asm volatile("s_waitcnt vmcnt(4)" ::: "memory");
  __builtin_amdgcn_sched_barrier(0);
  __builtin_amdgcn_s_barrier();
  __builtin_amdgcn_sched_barrier(0);

  f32x16 sA0, sA1, sB0, sB1;
  QK(0, sA0, sA1);

#define BODY(KT, C0, C1, N0, N1)                                          \
  {                                                                       \
    const int kt_b = (KT);                                                \
    if (kt_b + 2 < nt)                                                    \
      asm volatile("s_waitcnt vmcnt(4)" ::: "memory");                    \
    else                                                                  \
      asm volatile("s_waitcnt vmcnt(0)" ::: "memory");                    \
    __builtin_amdgcn_sched_barrier(0);                                    \
    __builtin_amdgcn_s_barrier();                                         \
    __builtin_amdgcn_sched_barrier(0);                                    \
    STAGE(kt_b + 3);                                                      \
    if (kt_b + 1 < nt && (kt_b + 1) * 64 < q0w + 32) QK(kt_b + 1, N0, N1);\
    FINISH(kt_b, C0, C1);                                                 \
  }

  for (int kt2 = 0; kt2 < nt; kt2 += 2) {
    BODY(kt2, sA0, sA1, sB0, sB1);
    BODY(kt2 + 1, sB0, sB1, sA0, sA1);
  }
#undef BODY

  const int b = bh >> 4, h = bh & 15;
  const float inv = 1.f / l_run;
  u16* aorow = ao + ((size_t)(b * TT) + qg) * CC + h * DD;
#pragma unroll
  for (int rg = 0; rg < 4; ++rg) {
    u16x4 t0v, t1v;
#pragma unroll
    for (int j = 0; j < 4; ++j) {
      t0v[j] = f2bf(o0[rg * 4 + j] * inv);
      t1v[j] = f2bf(o1[rg * 4 + j] * inv);
    }
    *(u16x4*)(aorow + 8 * rg + 4 * half) = t0v;
    *(u16x4*)(aorow + 32 + 8 * rg + 4 * half) = t1v;
  }
}

// -------------------------------------------------------------- launch ----
extern "C" void kernel_launch(void* const* d_in, const int* in_sizes, int n_in,
                              void* d_out, int out_size, void* d_ws, size_t ws_size,
                              hipStream_t stream) {
  const float* x  = (const float*)d_in[0];
  const float* Wa = (const float*)d_in[1];
  const float* ba = (const float*)d_in[2];
  const float* Wp = (const float*)d_in[3];
  const float* bp = (const float*)d_in[4];
  float* out = (float*)d_out;

  char* ws = (char*)d_ws;
  const size_t MB = 1ull << 20;
  u16* x_bf = (u16*)(ws);            // 8 MB  [4096][1024]
  u16* ao   = (u16*)(ws);            // 8 MB  alias (x_bf dead after QKV GEMM)
  u16* Wa_t = (u16*)(ws + 8 * MB);   // 6 MB  [3072][1024]
  u16* Wp_t = (u16*)(ws + 14 * MB);  // 2 MB  [1024][1024]
  u16* q_ws = (u16*)(ws + 16 * MB);  // 8 MB  [32][2048][64]
  u16* k_ws = (u16*)(ws + 24 * MB);  // 8 MB  [32][2048][64]
  u16* v_ws = (u16*)(ws + 32 * MB);  // 8 MB  [32][64][2048]

  static bool attr_set = []() {
    hipFuncSetAttribute((const void*)gemm_qkv256,
                        hipFuncAttributeMaxDynamicSharedMemorySize, 114688);
    hipFuncSetAttribute((const void*)attn_fwd,
                        hipFuncAttributeMaxDynamicSharedMemorySize, 65536);
    return true;
  }();
  (void)attr_set;

  hipLaunchKernelGGL(prep_all, dim3(160, 32), dim3(32, 32), 0, stream,
                     x, Wa, Wp, x_bf, Wa_t, Wp_t);
  hipLaunchKernelGGL(gemm_qkv256, dim3(256), dim3(512), 114688, stream,
                     x_bf, Wa_t, ba, q_ws, k_ws, v_ws);
  hipLaunchKernelGGL(attn_fwd, dim3(TT / 128, BB * HH), dim3(256), 65536, stream,
                     q_ws, k_ws, v_ws, ao);
  hipLaunchKernelGGL(gemm_proj, dim3(CC / 128, MDIM / 128), dim3(256), 0, stream,
                     ao, Wp_t, bp, out, MDIM, CC, CC);
}

// Round 17
// 104.080 us; speedup vs baseline: 1.1233x; 1.0402x over previous
//
#include <hip/hip_runtime.h>

typedef unsigned short u16;
typedef unsigned int u32;
typedef float f32x4 __attribute__((ext_vector_type(4)));
typedef float f32x16 __attribute__((ext_vector_type(16)));
typedef unsigned int u32x4 __attribute__((ext_vector_type(4)));
typedef unsigned int u32x2 __attribute__((ext_vector_type(2)));
typedef unsigned short u16x8 __attribute__((ext_vector_type(8)));
typedef unsigned short u16x4 __attribute__((ext_vector_type(4)));

#define DEV static __device__ __forceinline__

constexpr int BB = 2, TT = 2048, CC = 1024, HH = 16, DD = 64;
constexpr int MDIM = BB * TT;  // 4096

DEV u16 f2bf(float f) {
  unsigned int u = __builtin_bit_cast(unsigned int, f);
  u += 0x7fffu + ((u >> 16) & 1u);
  return (u16)(u >> 16);
}
DEV float bf2f(u16 h) {
  unsigned int u = ((unsigned int)h) << 16;
  return __builtin_bit_cast(float, u);
}
DEV void async16(const void* g, void* l) {
  __builtin_amdgcn_global_load_lds(
      (const __attribute__((address_space(1))) unsigned int*)g,
      (__attribute__((address_space(3))) unsigned int*)l, 16, 0, 0);
}
DEV void mfma16(f32x4& acc, u32x4 a, u32x4 b) {
  asm volatile("v_mfma_f32_16x16x32_bf16 %0, %1, %2, %0"
               : "+v"(acc)
               : "v"(a), "v"(b));
}
DEV void mfma32(f32x16& acc, u32x4 a, u32x4 b) {
  asm volatile("v_mfma_f32_32x32x16_bf16 %0, %1, %2, %0"
               : "+v"(acc)
               : "v"(a), "v"(b));
}
DEV u32 cvtpk(float lo, float hi) {
  u32 r;
  asm("v_cvt_pk_bf16_f32 %0, %1, %2" : "=v"(r) : "v"(lo), "v"(hi));
  return r;
}
DEV void pswap(u32& a, u32& b) {
#if __has_builtin(__builtin_amdgcn_permlane32_swap)
  u32x2 r = __builtin_amdgcn_permlane32_swap(a, b, false, false);
  a = r.x;
  b = r.y;
#else
  asm volatile("v_permlane32_swap_b32 %0, %1" : "+v"(a), "+v"(b));
#endif
}
DEV float exp2g(float x) {
#if __has_builtin(__builtin_amdgcn_exp2f)
  return __builtin_amdgcn_exp2f(x);
#else
  return exp2f(x);
#endif
}

// ---------------------------------------------------------------- prep ----
__global__ void prep_all(const float* __restrict__ x,
                         const float* __restrict__ Wa, const float* __restrict__ Wp,
                         u16* __restrict__ x_bf,
                         u16* __restrict__ Wa_t, u16* __restrict__ Wp_t) {
  __shared__ float tile[32][33];
  int bx = blockIdx.x;
  const int tx = threadIdx.x, ty = threadIdx.y;
  if (bx >= 128) {
    const int cb = (bx - 128) * 32 + blockIdx.y;
    const int i = (cb * 1024 + ty * 32 + tx) * 4;
    f32x4 v = *(const f32x4*)(x + i);
    u16x4 o;
#pragma unroll
    for (int j = 0; j < 4; ++j) o[j] = f2bf(v[j]);
    *(u16x4*)(x_bf + i) = o;
    return;
  }
  const float* in;
  u16* out;
  int Cc;
  if (bx < 96) { in = Wa; out = Wa_t; Cc = 3072; }
  else { bx -= 96; in = Wp; out = Wp_t; Cc = 1024; }
  const int R = 1024;
  const int x0 = bx * 32, y0 = blockIdx.y * 32;
  tile[ty][tx] = in[(size_t)(y0 + ty) * Cc + (x0 + tx)];
  __syncthreads();
  out[(size_t)(x0 + ty) * R + (y0 + tx)] = f2bf(tile[tx][ty]);
}

// -------------------------------------------------- qkv GEMM (256x192) ----
// R15-proven: counted-vmcnt 2-deep pipeline, 256 blocks = 1/CU, 8 waves.
__global__ __launch_bounds__(512, 2) void gemm_qkv256(
    const u16* __restrict__ A, const u16* __restrict__ Bt,
    const float* __restrict__ bias,
    u16* __restrict__ qw, u16* __restrict__ kw, u16* __restrict__ vw) {
  extern __shared__ char smem[];  // A: 2x32KB @0 | B: 2x24KB @64KB = 112KB
  const int K = CC, NT = K / 64;
  const int tid = threadIdx.x;
  const int lane = tid & 63, w = tid >> 6;
  const int g = lane >> 4, c16 = lane & 15;
  const int wm2 = (w >> 2) * 128, wn2 = (w & 3) * 48;

  const int wgid = blockIdx.x;
  const int xcd = wgid & 7, idx = wgid >> 3;
  const int patch = xcd * 2 + (idx >> 4);
  const int q = idx & 15;
  const int bys = (patch & 3) * 4 + (q & 3);
  const int bxs = (patch >> 2) * 4 + (q >> 2);
  const int brow = bys * 256, bcol = bxs * 192;

  const int lrow = lane >> 3;
  const int scol = ((lane & 7) ^ lrow) << 4;
  const int rswz = (c16 & 7) << 4;

  f32x4 acc[8][3];
#pragma unroll
  for (int m = 0; m < 8; ++m)
#pragma unroll
    for (int n = 0; n < 3; ++n) acc[m][n] = f32x4{0.f, 0.f, 0.f, 0.f};

  const size_t ldb = (size_t)K * 2;
  const char* Abase = (const char*)A + (size_t)brow * ldb;
  const char* Bbase = (const char*)Bt + (size_t)bcol * ldb;

  auto STAGE = [&](int kt) {
    const int par = kt & 1;
    char* Adst = smem + par * 32768;
    char* Bdst = smem + 65536 + par * 24576;
    const size_t koff = (size_t)kt * 128;
#pragma unroll
    for (int i = 0; i < 4; ++i) {
      const int c = w * 4 + i;
      const int row = c * 8 + lrow;
      async16(Abase + (size_t)row * ldb + koff + scol, Adst + c * 1024);
    }
#pragma unroll
    for (int i = 0; i < 3; ++i) {
      const int c = w * 3 + i;
      const int row = c * 8 + lrow;
      async16(Bbase + (size_t)row * ldb + koff + scol, Bdst + c * 1024);
    }
  };

  STAGE(0);
  STAGE(1);

  for (int kt = 0; kt < NT; ++kt) {
    const int par = kt & 1;
    if (kt + 1 < NT)
      asm volatile("s_waitcnt vmcnt(7)" ::: "memory");
    else
      asm volatile("s_waitcnt vmcnt(0)" ::: "memory");
    __builtin_amdgcn_sched_barrier(0);
    __builtin_amdgcn_s_barrier();
    __builtin_amdgcn_sched_barrier(0);
    const char* Ap = smem + par * 32768;
    const char* Bp = smem + 65536 + par * 24576;
#pragma unroll
    for (int kc = 0; kc < 2; ++kc) {
      const int cb = (kc * 64 + g * 16) ^ rswz;
      u32x4 af[8], bf[3];
#pragma unroll
      for (int m = 0; m < 8; ++m)
        af[m] = *(const u32x4*)(Ap + (wm2 + m * 16 + c16) * 128 + cb);
#pragma unroll
      for (int n = 0; n < 3; ++n)
        bf[n] = *(const u32x4*)(Bp + (wn2 + n * 16 + c16) * 128 + cb);
#pragma unroll
      for (int m = 0; m < 8; ++m)
#pragma unroll
        for (int n = 0; n < 3; ++n) mfma16(acc[m][n], af[m], bf[n]);
    }
    __builtin_amdgcn_sched_barrier(0);
    __builtin_amdgcn_s_barrier();
    __builtin_amdgcn_sched_barrier(0);
    if (kt + 2 < NT) STAGE(kt + 2);
  }

  u16* E = (u16*)smem;
#pragma unroll
  for (int n = 0; n < 3; ++n) {
    const float bv = bias[bcol + wn2 + n * 16 + c16];
#pragma unroll
    for (int m = 0; m < 8; ++m)
#pragma unroll
      for (int r = 0; r < 4; ++r)
        E[(wm2 + m * 16 + g * 4 + r) * 192 + wn2 + n * 16 + c16] =
            f2bf(acc[m][n][r] + bv);
  }
  __syncthreads();
#pragma unroll
  for (int i = 0; i < 12; ++i) {
    const int c = tid + i * 512;
    {  // row-major: q/k
      const int row = c / 24, col8 = (c % 24) * 8;
      const int colg = bcol + col8;
      if (colg < 2048) {
        const int which = colg >> 10, cc = colg & 1023, h = cc >> 6, d = cc & 63;
        const int rowg = brow + row, b = rowg >> 11, t = rowg & (TT - 1);
        u16x8 v8 = *(const u16x8*)&E[row * 192 + col8];
        u16* dst = (which == 0 ? qw : kw) + ((size_t)(b * HH + h) * TT + t) * DD + d;
        *(u16x8*)dst = v8;
      }
    }
    {  // col-major: v -> [d][t]
      const int col = c % 192, row8 = (c / 192) * 8;
      const int colg = bcol + col;
      if (colg >= 2048) {
        const int cc = colg & 1023, h = cc >> 6, d = cc & 63;
        const int rowg = brow + row8, b = rowg >> 11, t = rowg & (TT - 1);
        u16x8 v8;
#pragma unroll
        for (int j = 0; j < 8; ++j) v8[j] = E[(row8 + j) * 192 + col];
        u16* dst = vw + ((size_t)(b * HH + h) * DD + d) * TT + t;
        *(u16x8*)dst = v8;
      }
    }
  }
}

// ----------------------------------------------------------- proj GEMM ----
// R16: proj was the old 2-barrier m97 loop at 1 block/CU -- the structure's
// latency hiding comes from cross-block overlap (m114), absent with a single
// resident block, so every K-step's vmcnt(0) drain was fully exposed.
// Port the qkv256-proven counted-vmcnt 2-deep pipeline: vmcnt(8) mid-loop
// (never 0), stage(kt+2) into the retired buffer after the compute barrier.
// LDS: A 2x16KB + B 2x16KB = 64KB dynamic.
__global__ __launch_bounds__(256, 2) void gemm_proj(
    const u16* __restrict__ A, const u16* __restrict__ Bt,
    const float* __restrict__ bias, float* __restrict__ outF,
    int M, int N, int K) {
  extern __shared__ char smem_p[];  // A: 2x16KB @0 | B: 2x16KB @32KB
  const int NT = K / 64;
  const int tid = threadIdx.x;
  const int lane = tid & 63, w = tid >> 6;
  const int g = lane >> 4, c16 = lane & 15;
  const int wm = (w >> 1) * 64, wn = (w & 1) * 64;

  const int wgid = blockIdx.y * gridDim.x + blockIdx.x;
  const int xcd = wgid & 7, pi = wgid >> 3;
  const int bxs = pi & 7;
  const int bys = 4 * xcd + (pi >> 3);
  const int brow = bys * 128, bcol = bxs * 128;

  const int lrow = lane >> 3;
  const int scol = ((lane & 7) ^ lrow) << 4;
  const int rswz = (c16 & 7) << 4;

  f32x4 acc[4][4];
#pragma unroll
  for (int m = 0; m < 4; ++m)
#pragma unroll
    for (int n = 0; n < 4; ++n) acc[m][n] = f32x4{0.f, 0.f, 0.f, 0.f};

  const size_t ldb = (size_t)K * 2;
  const char* Abase = (const char*)A + (size_t)brow * ldb;
  const char* Bbase = (const char*)Bt + (size_t)bcol * ldb;

  auto STAGE = [&](int kt) {
    const int par = kt & 1;
    char* Adst = smem_p + par * 16384;
    char* Bdst = smem_p + 32768 + par * 16384;
    const size_t koff = (size_t)kt * 128;
#pragma unroll
    for (int i = 0; i < 4; ++i) {
      const int c = w * 4 + i;            // 16 chunks x 1KB per tile
      const int row = c * 8 + lrow;
      async16(Abase + (size_t)row * ldb + koff + scol, Adst + c * 1024);
      async16(Bbase + (size_t)row * ldb + koff + scol, Bdst + c * 1024);
    }
  };

  STAGE(0);
  STAGE(1);

  for (int kt = 0; kt < NT; ++kt) {
    const int par = kt & 1;
    if (kt + 1 < NT)
      asm volatile("s_waitcnt vmcnt(8)" ::: "memory");  // kt landed; kt+1 in flight
    else
      asm volatile("s_waitcnt vmcnt(0)" ::: "memory");
    __builtin_amdgcn_sched_barrier(0);
    __builtin_amdgcn_s_barrier();
    __builtin_amdgcn_sched_barrier(0);
    const char* Ap = smem_p + par * 16384;
    const char* Bp = smem_p + 32768 + par * 16384;
#pragma unroll
    for (int kc = 0; kc < 2; ++kc) {
      const int cb = (kc * 64 + g * 16) ^ rswz;
      u32x4 af[4], bf8[4];
#pragma unroll
      for (int m = 0; m < 4; ++m)
        af[m] = *(const u32x4*)(Ap + (wm + m * 16 + c16) * 128 + cb);
#pragma unroll
      for (int n = 0; n < 4; ++n)
        bf8[n] = *(const u32x4*)(Bp + (wn + n * 16 + c16) * 128 + cb);
#pragma unroll
      for (int m = 0; m < 4; ++m)
#pragma unroll
        for (int n = 0; n < 4; ++n) mfma16(acc[m][n], af[m], bf8[n]);
    }
    __builtin_amdgcn_sched_barrier(0);
    __builtin_amdgcn_s_barrier();       // all waves done reading buf[par]
    __builtin_amdgcn_sched_barrier(0);
    if (kt + 2 < NT) STAGE(kt + 2);
  }

  float* Ef = (float*)smem_p;  // [64][128] f32 = 32KB
#pragma unroll
  for (int pass = 0; pass < 2; ++pass) {
    __syncthreads();
    if ((wm >> 6) == pass) {
#pragma unroll
      for (int n = 0; n < 4; ++n) {
        const float bv = bias[bcol + wn + n * 16 + c16];
#pragma unroll
        for (int m = 0; m < 4; ++m)
#pragma unroll
          for (int r = 0; r < 4; ++r)
            Ef[(m * 16 + g * 4 + r) * 128 + wn + n * 16 + c16] = acc[m][n][r] + bv;
      }
    }
    __syncthreads();
#pragma unroll
    for (int i = 0; i < 8; ++i) {
      const int chunk = tid + i * 256;
      const int row = chunk >> 5;
      const int c4 = (chunk & 31) * 4;
      f32x4 v4 = *(const f32x4*)&Ef[row * 128 + c4];
      *(f32x4*)&outF[(size_t)(brow + pass * 64 + row) * N + bcol + c4] = v4;
    }
  }
}

// ----------------------------------------------------------- attention ----
// R9 structure EXACT (proven 41.8us) + R16 XCD-bh-locality block mapping:
// each XCD owns 4 heads entirely (K/V per XCD = 4 x 512KB = 2MB <= 4MB L2),
// eliminating the 3.4x cross-XCD K/V re-fetch (FETCH 55MB). Complementary
// qb pairing preserved: co-resident blocks id, id+256 get qi and 15-qi.
__global__ __launch_bounds__(256) void attn_fwd(
    const u16* __restrict__ qw, const u16* __restrict__ kw,
    const u16* __restrict__ vw, u16* __restrict__ ao) {
  extern __shared__ u16 smem_a[];  // [4][64*64] K, then [4][64*64] V (64KB)
  const int tid = threadIdx.x;
  const int lane = tid & 63, w = tid >> 6;
  const int ql = lane & 31, half = lane >> 5;
  // bh/qb from XCD-locality mapping (bijective over 512 blocks)
  const int id = blockIdx.x;
  const int xcd = id & 7, slot = id >> 3;
  const int bhl = slot >> 4, qi = slot & 15;
  const int bh = (xcd << 2) + bhl;
  const int qb = (bhl & 2) ? (15 - qi) : qi;
  const int q0w = qb * 128 + w * 32;
  const int qg = q0w + ql;
  const int lrow = lane >> 3;
  const int scol = ((lane & 7) ^ lrow) << 4;
  const int rswz = (ql & 7) << 4;

  u32x4 qf[4];
  {
    const u16* qrow = qw + ((size_t)bh * TT + qg) * DD;
    const float qs = 0.125f * 1.44269504f;
#pragma unroll
    for (int dwin = 0; dwin < 4; ++dwin) {
      u16x8 u = *(const u16x8*)(qrow + dwin * 16 + half * 8);
      u16x8 s;
#pragma unroll
      for (int j = 0; j < 8; ++j) s[j] = f2bf(bf2f(u[j]) * qs);
      qf[dwin] = __builtin_bit_cast(u32x4, s);
    }
  }

  f32x16 o0, o1;
#pragma unroll
  for (int i = 0; i < 16; ++i) { o0[i] = 0.f; o1[i] = 0.f; }
  float l_run = 0.f;

  const char* kbase = (const char*)kw + ((size_t)bh * TT) * 128;
  const char* vbase = (const char*)vw + ((size_t)bh * DD) * (TT * 2);

  const int nt = 2 * qb + 2;  // always even

  auto kptr = [&](int b) { return (char*)(smem_a + (b & 3) * 4096); };
  auto vptr = [&](int b) { return (char*)(smem_a + 16384 + (b & 3) * 4096); };

  auto STAGE = [&](int kt_) {
    if (kt_ >= nt) return;
    const int t0_ = kt_ * 64;
#pragma unroll
    for (int i_ = 0; i_ < 2; ++i_) {
      const int chunk = w * 2 + i_;
      const int row = chunk * 8 + lrow;
      async16(kbase + (size_t)(t0_ + row) * 128 + scol, kptr(kt_) + chunk * 1024);
      async16(vbase + (size_t)row * (TT * 2) + (size_t)t0_ * 2 + scol,
              vptr(kt_) + chunk * 1024);
    }
  };

  auto QK = [&](int kt_, f32x16& sa, f32x16& sb) {
    const char* Kc = kptr(kt_);
#pragma unroll
    for (int i = 0; i < 16; ++i) { sa[i] = 0.f; sb[i] = 0.f; }
    __builtin_amdgcn_s_setprio(1);
#pragma unroll
    for (int dwin = 0; dwin < 4; ++dwin) {
      const int cb = (dwin * 32 + half * 16) ^ rswz;
      u32x4 ak0 = *(const u32x4*)(Kc + (0 + ql) * 128 + cb);
      u32x4 ak1 = *(const u32x4*)(Kc + (32 + ql) * 128 + cb);
      mfma32(sa, ak0, qf[dwin]);
      mfma32(sb, ak1, qf[dwin]);
    }
    __builtin_amdgcn_s_setprio(0);
  };

  auto FINISH = [&](int kt_, f32x16& s0, f32x16& s1) {
    const int t0 = kt_ * 64;
    if (t0 >= q0w + 32) return;
    if (t0 + 63 > q0w) {
      const int kb = t0 + 4 * half - qg;
#pragma unroll
      for (int r = 0; r < 16; ++r) {
        const int ko = (r & 3) + 8 * (r >> 2);
        if (kb + ko > 0) s0[r] = -1e30f;
        if (kb + 32 + ko > 0) s1[r] = -1e30f;
      }
    }
#pragma unroll
    for (int i = 0; i < 16; ++i) {
      s0[i] = exp2g(s0[i]);
      s1[i] = exp2g(s1[i]);
    }
    float a8[8];
#pragma unroll
    for (int i = 0; i < 8; ++i)
      a8[i] = (s0[i] + s0[i + 8]) + (s1[i] + s1[i + 8]);
    float rs = ((a8[0] + a8[1]) + (a8[2] + a8[3])) + ((a8[4] + a8[5]) + (a8[6] + a8[7]));
    rs += __shfl_xor(rs, 32, 64);
    l_run += rs;

    u32x4 pf[4];
#pragma unroll
    for (int win = 0; win < 4; ++win) {
      const int b = (win & 1) * 8;
      u32 w0, w1, w2, w3;
      if (win < 2) {
        w0 = cvtpk(s0[b + 0], s0[b + 1]); w2 = cvtpk(s0[b + 4], s0[b + 5]);
        w1 = cvtpk(s0[b + 2], s0[b + 3]); w3 = cvtpk(s0[b + 6], s0[b + 7]);
      } else {
        w0 = cvtpk(s1[b + 0], s1[b + 1]); w2 = cvtpk(s1[b + 4], s1[b + 5]);
        w1 = cvtpk(s1[b + 2], s1[b + 3]); w3 = cvtpk(s1[b + 6], s1[b + 7]);
      }
      pswap(w0, w2);
      pswap(w1, w3);
      pf[win] = u32x4{w0, w1, w2, w3};
    }
    const char* Vc = vptr(kt_);
    __builtin_amdgcn_s_setprio(1);
#pragma unroll
    for (int win = 0; win < 4; ++win) {
      const int cb = (win * 32 + half * 16) ^ rswz;
      u32x4 av0 = *(const u32x4*)(Vc + (0 + ql) * 128 + cb);
      u32x4 av1 = *(const u32x4*)(Vc + (32 + ql) * 128 + cb);
      mfma32(o0, av0, pf[win]);
      mfma32(o1, av1, pf[win]);
    }
    __builtin_amdgcn_s_setprio(0);
  };

  STAGE(0);
  STAGE(1);
  STAGE(2);
  if (nt >= 3)
    asm volatile("s_waitcnt vmcnt(8)" ::: "memory");
  else
    asm volatile("s_waitcnt vmcnt(4)" ::: "memory");
  __builtin_amdgcn_sched_barrier(0);
  __builtin_amdgcn_s_barrier();
  __builtin_amdgcn_sched_barrier(0);

  f32x16 sA0, sA1, sB0, sB1;
  QK(0, sA0, sA1);

#define BODY(KT, C0, C1, N0, N1)                                          \
  {                                                                       \
    const int kt_b = (KT);                                                \
    if (kt_b + 2 < nt)                                                    \
      asm volatile("s_waitcnt vmcnt(4)" ::: "memory");                    \
    else                                                                  \
      asm volatile("s_waitcnt vmcnt(0)" ::: "memory");                    \
    __builtin_amdgcn_sched_barrier(0);                                    \
    __builtin_amdgcn_s_barrier();                                         \
    __builtin_amdgcn_sched_barrier(0);                                    \
    STAGE(kt_b + 3);                                                      \
    if (kt_b + 1 < nt && (kt_b + 1) * 64 < q0w + 32) QK(kt_b + 1, N0, N1);\
    FINISH(kt_b, C0, C1);                                                 \
  }

  for (int kt2 = 0; kt2 < nt; kt2 += 2) {
    BODY(kt2, sA0, sA1, sB0, sB1);
    BODY(kt2 + 1, sB0, sB1, sA0, sA1);
  }
#undef BODY

  const int b = bh >> 4, h = bh & 15;
  const float inv = 1.f / l_run;
  u16* aorow = ao + ((size_t)(b * TT) + qg) * CC + h * DD;
#pragma unroll
  for (int rg = 0; rg < 4; ++rg) {
    u16x4 t0v, t1v;
#pragma unroll
    for (int j = 0; j < 4; ++j) {
      t0v[j] = f2bf(o0[rg * 4 + j] * inv);
      t1v[j] = f2bf(o1[rg * 4 + j] * inv);
    }
    *(u16x4*)(aorow + 8 * rg + 4 * half) = t0v;
    *(u16x4*)(aorow + 32 + 8 * rg + 4 * half) = t1v;
  }
}

// -------------------------------------------------------------- launch ----
extern "C" void kernel_launch(void* const* d_in, const int* in_sizes, int n_in,
                              void* d_out, int out_size, void* d_ws, size_t ws_size,
                              hipStream_t stream) {
  const float* x  = (const float*)d_in[0];
  const float* Wa = (const float*)d_in[1];
  const float* ba = (const float*)d_in[2];
  const float* Wp = (const float*)d_in[3];
  const float* bp = (const float*)d_in[4];
  float* out = (float*)d_out;

  char* ws = (char*)d_ws;
  const size_t MB = 1ull << 20;
  u16* x_bf = (u16*)(ws);            // 8 MB  [4096][1024]
  u16* ao   = (u16*)(ws);            // 8 MB  alias (x_bf dead after QKV GEMM)
  u16* Wa_t = (u16*)(ws + 8 * MB);   // 6 MB  [3072][1024]
  u16* Wp_t = (u16*)(ws + 14 * MB);  // 2 MB  [1024][1024]
  u16* q_ws = (u16*)(ws + 16 * MB);  // 8 MB  [32][2048][64]
  u16* k_ws = (u16*)(ws + 24 * MB);  // 8 MB  [32][2048][64]
  u16* v_ws = (u16*)(ws + 32 * MB);  // 8 MB  [32][64][2048]

  static bool attr_set = []() {
    hipFuncSetAttribute((const void*)gemm_qkv256,
                        hipFuncAttributeMaxDynamicSharedMemorySize, 114688);
    hipFuncSetAttribute((const void*)gemm_proj,
                        hipFuncAttributeMaxDynamicSharedMemorySize, 65536);
    hipFuncSetAttribute((const void*)attn_fwd,
                        hipFuncAttributeMaxDynamicSharedMemorySize, 65536);
    return true;
  }();
  (void)attr_set;

  hipLaunchKernelGGL(prep_all, dim3(160, 32), dim3(32, 32), 0, stream,
                     x, Wa, Wp, x_bf, Wa_t, Wp_t);
  hipLaunchKernelGGL(gemm_qkv256, dim3(256), dim3(512), 114688, stream,
                     x_bf, Wa_t, ba, q_ws, k_ws, v_ws);
  hipLaunchKernelGGL(attn_fwd, dim3(512), dim3(256), 65536, stream,
                     q_ws, k_ws, v_ws, ao);
  hipLaunchKernelGGL(gemm_proj, dim3(CC / 128, MDIM / 128), dim3(256), 65536, stream,
                     ao, Wp_t, bp, out, MDIM, CC, CC);
}